// Round 3
// baseline (550.122 us; speedup 1.0000x reference)
//
#include <hip/hip_runtime.h>
#include <hip/hip_cooperative_groups.h>
#include <cstddef>
#include <math.h>

namespace cg = cooperative_groups;

// Problem constants (match reference)
#define S_TOK 4096
#define MDIM  2048
#define NE    32
#define CAP   256     // ceil(4096/32 * 1.0 * 2) = 256
#define TPB   256
#define NBLK  256     // cooperative grid: 1 block per CU
#define TOKB  4       // tokens per gating sub-batch
#define TPB_TOK 16    // tokens per block total (4096/256)

// Workspace layout. Fields before `e1a` are zeroed in phase 0.
struct Ws {
    int   counts[NE];        // pre-capacity per-expert token counts
    int   ecount[NE];        // per-expert assigned-list length (== counts)
    int   loc_s[S_TOK];      // sum of kept locations per token
    int   keptA[S_TOK];      // top-1 expert kept?
    int   keptB[S_TOK];      // top-2 expert kept?
    float gate_sum[NE];      // sum of softmax gates per expert (for me)
    // --- always written before read ---
    int   e1a[S_TOK];
    int   e2a[S_TOK];
    float g1a[S_TOK];
    float g2a[S_TOK];
    int   etok[NE * S_TOK];  // per-expert assigned token ids
    float eval[NE * S_TOK];  // per-expert assigned raw logits
};

// Single cooperative kernel: phases separated by grid.sync().
//   0: zero ws accumulators
//   1: logits (fp64 acc) + softmax + top-2 + expert lists   (all 256 blocks)
//   2: per-expert capacity filter + locations               (blocks 0..31)
//   3: stream-write combine_weights/dispatch_mask rows; block 0 adds
//      l_aux + exp_counts
__global__ __launch_bounds__(TPB) void k_all(const float* __restrict__ x,
                                             const float* __restrict__ wg,
                                             Ws* __restrict__ ws,
                                             float* __restrict__ out) {
    cg::grid_group grid = cg::this_grid();
    const int tid = threadIdx.x;
    const int bid = blockIdx.x;

    __shared__ float4 xs4[TOKB * 512];           // 32 KB: x tile
    __shared__ double part[8][NE][TOKB];         // 8 KB: partial dots
    __shared__ float  logitsF[TOKB][NE];         // fp32 logits
    __shared__ float  gsumL[NE];
    __shared__ float  vals[S_TOK];               // 16 KB (phase 2)
    __shared__ int    toks[S_TOK];               // 16 KB (phase 2)
    __shared__ unsigned char kept[S_TOK];        // 4 KB  (phase 2)

    // ---- Phase 0: zero ws accumulator region ----
    {
        const int nInt = (int)(offsetof(Ws, e1a) / sizeof(int));
        int* w = (int*)ws;
        for (int i = bid * TPB + tid; i < nInt; i += NBLK * TPB) w[i] = 0;
    }
    if (tid < NE) gsumL[tid] = 0.f;
    grid.sync();

    // ---- Phase 1: gating (16 tokens per block, 4 sub-batches of 4) ----
    const float4* x4  = (const float4*)x;
    const float4* wg4 = (const float4*)wg;       // wg row = 512 float4
    const int e   = tid & 31;
    const int seg = tid >> 5;                    // 0..7
    const int lane = tid & 63;
    const int half = lane >> 5;                  // 0/1
    const int grp  = (tid >> 6) * 2 + half;      // local token id within sub-batch
    const int le   = lane & 31;

    for (int it = 0; it < TPB_TOK / TOKB; ++it) {
        const int t0 = bid * TPB_TOK + it * TOKB;

        #pragma unroll
        for (int k = 0; k < (TOKB * 512) / TPB; ++k) {
            int idx = tid + k * TPB;
            xs4[idx] = x4[(size_t)t0 * 512 + idx];
        }
        __syncthreads();

        double acc[TOKB];
        #pragma unroll
        for (int i = 0; i < TOKB; ++i) acc[i] = 0.0;
        for (int j4 = 0; j4 < 64; ++j4) {
            float4 w = wg4[e * 512 + seg * 64 + j4];
            #pragma unroll
            for (int tt = 0; tt < TOKB; ++tt) {
                float4 xv = xs4[tt * 512 + seg * 64 + j4];   // LDS broadcast
                acc[tt] += (double)xv.x * w.x + (double)xv.y * w.y +
                           (double)xv.z * w.z + (double)xv.w * w.w;
            }
        }
        #pragma unroll
        for (int tt = 0; tt < TOKB; ++tt) part[seg][e][tt] = acc[tt];
        __syncthreads();

        if (tid < TOKB * 32) {
            int tok = tid >> 5;
            int ee  = tid & 31;
            double s = 0.0;
            #pragma unroll
            for (int sg = 0; sg < 8; ++sg) s += part[sg][ee][tok];
            logitsF[tok][ee] = (float)s;
        }
        __syncthreads();

        if (grp < TOKB) {
            float l = logitsF[grp][le];

            // top-1 (ties -> lower index, matching jax.lax.top_k)
            float v1 = l; int e1 = le;
            #pragma unroll
            for (int m = 16; m >= 1; m >>= 1) {
                float ov = __shfl_xor(v1, m);
                int   oi = __shfl_xor(e1, m);
                if (ov > v1 || (ov == v1 && oi < e1)) { v1 = ov; e1 = oi; }
            }
            // top-2
            float v2 = (le == e1) ? -INFINITY : l;
            int   e2 = (le == e1) ? 0x7fffffff : le;
            #pragma unroll
            for (int m = 16; m >= 1; m >>= 1) {
                float ov = __shfl_xor(v2, m);
                int   oi = __shfl_xor(e2, m);
                if (ov > v2 || (ov == v2 && oi < e2)) { v2 = ov; e2 = oi; }
            }
            // softmax
            float p = expf(l - v1);
            float ssum = p;
            #pragma unroll
            for (int m = 16; m >= 1; m >>= 1) ssum += __shfl_xor(ssum, m);
            float gate = p / ssum;
            atomicAdd(&gsumL[le], gate);

            float g1 = __shfl(gate, (half << 5) + e1);
            float g2 = __shfl(gate, (half << 5) + e2);

            if (le == 0) {
                int t = t0 + grp;
                atomicAdd(&ws->counts[e1], 1);
                atomicAdd(&ws->counts[e2], 1);
                int i1 = atomicAdd(&ws->ecount[e1], 1);
                ws->etok[e1 * S_TOK + i1] = t;
                ws->eval[e1 * S_TOK + i1] = v1;
                int i2 = atomicAdd(&ws->ecount[e2], 1);
                ws->etok[e2 * S_TOK + i2] = t;
                ws->eval[e2 * S_TOK + i2] = v2;
                ws->e1a[t] = e1; ws->e2a[t] = e2;
                ws->g1a[t] = g1; ws->g2a[t] = g2;
            }
        }
        __syncthreads();   // iteration boundary: protects xs4/part/logitsF reuse
    }
    if (tid < NE) atomicAdd(&ws->gate_sum[tid], gsumL[tid]);
    grid.sync();

    // ---- Phase 2: capacity filter (blocks 0..31, expert = bid) ----
    if (bid < NE) {
        const int ee = bid;
        const int n = ws->ecount[ee];

        for (int i = tid; i < n; i += TPB) {
            vals[i] = ws->eval[ee * S_TOK + i];
            toks[i] = ws->etok[ee * S_TOK + i];
        }
        __syncthreads();

        for (int i = tid; i < n; i += TPB) {
            float v = vals[i];
            int   t = toks[i];
            // dense rank: zeros (S-n) outrank v if v<0; ties -> lower index
            int rank = (v < 0.f) ? (S_TOK - n) : 0;
            int alt  = 0;
            for (int j = 0; j < n; ++j) {
                float vj = vals[j]; int tj = toks[j];
                rank += (vj > v || (vj == v && tj < t)) ? 1 : 0;
                alt  += (tj < t) ? 1 : 0;
            }
            if (v == 0.f) rank += t - alt;   // zeros tie with v==0 at lower index
            kept[i] = (rank < CAP) ? 1 : 0;
        }
        __syncthreads();

        for (int i = tid; i < n; i += TPB) {
            if (!kept[i]) continue;
            int t = toks[i];
            int loc = 0;
            for (int j = 0; j < n; ++j) loc += (kept[j] && toks[j] < t) ? 1 : 0;
            atomicAdd(&ws->loc_s[t], loc);
            if (ws->e1a[t] == e) { }
            if (ws->e1a[t] == ee) ws->keptA[t] = 1;
            else                  ws->keptB[t] = 1;
        }
    }
    grid.sync();

    // ---- Phase 3: stream outputs (16 token-rows per block) ----
    for (int tt = 0; tt < TPB_TOK; ++tt) {
        const int t = bid * TPB_TOK + tt;
        // every thread derives p1/p2/w1/w2 redundantly (broadcast loads)
        int p1 = -1, p2 = -1;
        float w1 = 0.f, w2 = 0.f;
        int kA = ws->keptA[t], kB = ws->keptB[t];
        int loc = ws->loc_s[t];
        if ((kA | kB) && loc < CAP) {
            float g1 = ws->g1a[t], g2 = ws->g2a[t];
            float d = (kA ? g1 : 0.f) + (kB ? g2 : 0.f);
            d = fmaxf(d, 1.1920929e-07f);        // finfo(f32).eps clip
            if (kA) { p1 = ws->e1a[t] * CAP + loc; w1 = g1 / d; }
            if (kB) { p2 = ws->e2a[t] * CAP + loc; w2 = g2 / d; }
        }

        float* cw = out + 1 + (size_t)t * (NE * CAP);
        float* dm = out + 1 + (size_t)S_TOK * NE * CAP + (size_t)t * (NE * CAP);

        // head scalars (row offsets 0..2) + tail scalar (offset 8191):
        // d_out+1 is only 4B-aligned, so rows split 3 + 2047*float4 + 1
        if (tid < 4) {
            int off = (tid < 3) ? tid : (NE * CAP - 1);
            float c = 0.f, m = 0.f;
            if (off == p1) { c = w1; m = 1.f; }
            if (off == p2) { c += w2; m = 1.f; }
            cw[off] = c; dm[off] = m;
        }
        float4* cw4 = (float4*)(cw + 3);
        float4* dm4 = (float4*)(dm + 3);
        for (int f = tid; f < 2047; f += TPB) {
            int base = 3 + f * 4;
            float4 c = {0.f, 0.f, 0.f, 0.f};
            float4 m = {0.f, 0.f, 0.f, 0.f};
            if (p1 >= base && p1 < base + 4) { ((float*)&c)[p1 - base] = w1; ((float*)&m)[p1 - base] = 1.f; }
            if (p2 >= base && p2 < base + 4) { ((float*)&c)[p2 - base] += w2; ((float*)&m)[p2 - base] = 1.f; }
            cw4[f] = c; dm4[f] = m;
        }
    }

    // l_aux + exp_counts (block 0)
    if (bid == 0 && tid < 64) {
        float partial = 0.f;
        if (tid < NE) {
            int c = ws->counts[tid];
            out[1 + 2 * (size_t)S_TOK * NE * CAP + tid] = (float)c;
            float me = ws->gate_sum[tid] / (float)S_TOK;
            float ce = (float)c / (float)S_TOK;
            partial = me * ce;
        }
        #pragma unroll
        for (int m = 16; m >= 1; m >>= 1) partial += __shfl_xor(partial, m);
        if (tid == 0) out[0] = partial * 16.0f;   // mean*E*E/K = sum/1024*1024/2*... = sum*16
    }
}

extern "C" void kernel_launch(void* const* d_in, const int* in_sizes, int n_in,
                              void* d_out, int out_size, void* d_ws, size_t ws_size,
                              hipStream_t stream) {
    const float* x  = (const float*)d_in[0];
    const float* wg = (const float*)d_in[1];
    float* out = (float*)d_out;
    Ws* ws = (Ws*)d_ws;

    void* args[] = { (void*)&x, (void*)&wg, (void*)&ws, (void*)&out };
    hipLaunchCooperativeKernel((const void*)k_all, dim3(NBLK), dim3(TPB),
                               args, 0, stream);
}

// Round 4
// 405.838 us; speedup vs baseline: 1.3555x; 1.3555x over previous
//
#include <hip/hip_runtime.h>
#include <cstddef>
#include <math.h>

// Problem constants (match reference)
#define S_TOK 4096
#define MDIM  2048
#define NE    32
#define CAP   256     // ceil(4096/32 * 1.0 * 2) = 256
#define TPB   256
#define TOKB  4       // tokens per block in gating kernel

// Atomic-free workspace: every field is written by an earlier kernel in the
// stream before it is read — NO zero-initialization pass needed.
struct Ws {
    int    e1a[S_TOK];        // top-1 expert per token
    int    e2a[S_TOK];        // top-2 expert per token
    float  g1a[S_TOK];        // softmax gate of top-1
    float  g2a[S_TOK];        // softmax gate of top-2
    float  v1a[S_TOK];        // raw top-1 logit
    float  v2a[S_TOK];        // raw top-2 logit
    int    keptA[S_TOK];      // init 0 by k_gate; set by k_capacity
    int    keptB[S_TOK];
    int    locA[S_TOK];       // init 0 by k_gate; set by k_capacity (kept only)
    int    locB[S_TOK];
    int    counts[NE];        // pre-capacity per-expert counts (k_capacity)
    double gate_sum[NE];      // per-expert softmax-gate column sums (k_capacity)
    float  gates[S_TOK * NE]; // full softmax gates matrix (k_gate)
};

// Kernel 1: logits (fp64 accumulate), softmax, top-2. One block = TOKB tokens.
// Thread (e=tid&31, seg=tid>>5) computes a 256-wide dot segment for expert e.
// Writes only per-token fields (each token owned by one lane) — no atomics.
__global__ __launch_bounds__(TPB) void k_gate(const float* __restrict__ x,
                                              const float* __restrict__ wg,
                                              Ws* __restrict__ ws) {
    __shared__ float4 xs4[TOKB * 512];           // 32 KB: x tile
    __shared__ double part[8][NE][TOKB];         // 8 KB: partial dots
    __shared__ float  logitsF[TOKB][NE];         // fp32 logits (match np values)

    const int tid = threadIdx.x;
    const int t0  = blockIdx.x * TOKB;

    // stage x tile (coalesced float4)
    const float4* x4 = (const float4*)x;
    #pragma unroll
    for (int k = 0; k < (TOKB * 512) / TPB; ++k) {
        int idx = tid + k * TPB;
        xs4[idx] = x4[(size_t)t0 * 512 + idx];
    }
    __syncthreads();

    const int e   = tid & 31;
    const int seg = tid >> 5;   // 0..7
    double acc[TOKB];
    #pragma unroll
    for (int i = 0; i < TOKB; ++i) acc[i] = 0.0;

    const float4* wg4 = (const float4*)wg;       // wg row = 512 float4
    for (int j4 = 0; j4 < 64; ++j4) {
        float4 w = wg4[e * 512 + seg * 64 + j4];
        #pragma unroll
        for (int tt = 0; tt < TOKB; ++tt) {
            float4 xv = xs4[tt * 512 + seg * 64 + j4];   // LDS broadcast
            acc[tt] += (double)xv.x * w.x + (double)xv.y * w.y +
                       (double)xv.z * w.z + (double)xv.w * w.w;
        }
    }
    #pragma unroll
    for (int tt = 0; tt < TOKB; ++tt) part[seg][e][tt] = acc[tt];
    __syncthreads();

    if (tid < TOKB * 32) {
        int tok = tid >> 5;
        int ee  = tid & 31;
        double s = 0.0;
        #pragma unroll
        for (int sg = 0; sg < 8; ++sg) s += part[sg][ee][tok];
        logitsF[tok][ee] = (float)s;
    }
    __syncthreads();

    // Per-token top-2 + softmax. Each 32-lane half-wave handles one token.
    const int lane = tid & 63;
    const int half = lane >> 5;                  // 0/1
    const int grp  = (tid >> 6) * 2 + half;      // local token id
    const int le   = lane & 31;

    if (grp < TOKB) {
        float l = logitsF[grp][le];
        const int t = t0 + grp;

        // top-1 (ties -> lower index, matching jax.lax.top_k)
        float v1 = l; int e1 = le;
        #pragma unroll
        for (int m = 16; m >= 1; m >>= 1) {
            float ov = __shfl_xor(v1, m);
            int   oi = __shfl_xor(e1, m);
            if (ov > v1 || (ov == v1 && oi < e1)) { v1 = ov; e1 = oi; }
        }
        // top-2
        float v2 = (le == e1) ? -INFINITY : l;
        int   e2 = (le == e1) ? 0x7fffffff : le;
        #pragma unroll
        for (int m = 16; m >= 1; m >>= 1) {
            float ov = __shfl_xor(v2, m);
            int   oi = __shfl_xor(e2, m);
            if (ov > v2 || (ov == v2 && oi < e2)) { v2 = ov; e2 = oi; }
        }
        // softmax
        float p = expf(l - v1);
        float ssum = p;
        #pragma unroll
        for (int m = 16; m >= 1; m >>= 1) ssum += __shfl_xor(ssum, m);
        float gate = p / ssum;

        ws->gates[t * NE + le] = gate;           // full gates row (for gate_sum)

        float g1 = __shfl(gate, (half << 5) + e1);
        float g2 = __shfl(gate, (half << 5) + e2);

        if (le == 0) {
            ws->e1a[t] = e1;  ws->e2a[t] = e2;
            ws->g1a[t] = g1;  ws->g2a[t] = g2;
            ws->v1a[t] = v1;  ws->v2a[t] = v2;
            ws->keptA[t] = 0; ws->keptB[t] = 0;
            ws->locA[t]  = 0; ws->locB[t]  = 0;
        }
    }
}

// Kernel 2: per-expert capacity filter (exact dense-column rank semantics of
// top_k over topk_masked_gates.T, zeros included) + kept-token locations +
// counts + gate column sum. One block per expert; builds its own token list
// from e1a/e2a (order-independent math), so no global atomics anywhere.
__global__ __launch_bounds__(256) void k_capacity(Ws* __restrict__ ws) {
    __shared__ float vals[S_TOK];
    __shared__ int   toks[S_TOK];
    __shared__ unsigned char kept[S_TOK];
    __shared__ int   cnt;
    __shared__ double gred[4];

    const int e = blockIdx.x;
    const int tid = threadIdx.x;
    if (tid == 0) cnt = 0;
    __syncthreads();

    // build this expert's assigned-token list + column gate sum
    double gs = 0.0;
    for (int i = tid; i < S_TOK; i += 256) {
        gs += (double)ws->gates[i * NE + e];
        int a1 = ws->e1a[i];
        int a2 = ws->e2a[i];
        float v; bool hit = false;
        if (a1 == e)      { v = ws->v1a[i]; hit = true; }
        else if (a2 == e) { v = ws->v2a[i]; hit = true; }
        if (hit) {
            int k = atomicAdd(&cnt, 1);   // LDS atomic; list order irrelevant
            vals[k] = v; toks[k] = i;
        }
    }
    // block-reduce gate sum (4 waves)
    #pragma unroll
    for (int m = 32; m >= 1; m >>= 1) gs += __shfl_xor(gs, m);
    if ((tid & 63) == 0) gred[tid >> 6] = gs;
    __syncthreads();
    const int n = cnt;
    if (tid == 0) {
        ws->counts[e]   = n;
        ws->gate_sum[e] = gred[0] + gred[1] + gred[2] + gred[3];
    }

    for (int i = tid; i < n; i += 256) {
        float v = vals[i];
        int   t = toks[i];
        // dense rank: zeros (S-n of them) outrank v if v<0; ties -> lower index
        int rank = (v < 0.f) ? (S_TOK - n) : 0;
        int alt  = 0;
        for (int j = 0; j < n; ++j) {
            float vj = vals[j]; int tj = toks[j];
            rank += (vj > v || (vj == v && tj < t)) ? 1 : 0;
            alt  += (tj < t) ? 1 : 0;
        }
        if (v == 0.f) rank += t - alt;   // zeros tie with v==0 at lower index
        kept[i] = (rank < CAP) ? 1 : 0;
    }
    __syncthreads();

    for (int i = tid; i < n; i += 256) {
        if (!kept[i]) continue;
        int t = toks[i];
        int loc = 0;
        for (int j = 0; j < n; ++j) loc += (kept[j] && toks[j] < t) ? 1 : 0;
        if (ws->e1a[t] == e) { ws->keptA[t] = 1; ws->locA[t] = loc; }
        else                 { ws->keptB[t] = 1; ws->locB[t] = loc; }
    }
}

// Kernel 3: scatter nonzeros of combine_weights/dispatch_mask (blocks 0..15)
// + l_aux and exp_counts (block 16).
__global__ __launch_bounds__(256) void k_scatter_final(const Ws* __restrict__ ws,
                                                       float* __restrict__ out) {
    if (blockIdx.x < 16) {
        int t = blockIdx.x * 256 + threadIdx.x;
        int kA = ws->keptA[t], kB = ws->keptB[t];
        if (!(kA | kB)) return;
        float g1 = ws->g1a[t], g2 = ws->g2a[t];
        float d = (kA ? g1 : 0.f) + (kB ? g2 : 0.f);
        d = fmaxf(d, 1.1920929e-07f);            // finfo(f32).eps clip
        int loc = ws->locA[t] + ws->locB[t];     // unkept entries are 0
        if (loc >= CAP) return;                  // one_hot out-of-range -> zeros
        float* cw = out + 1;
        float* dm = out + 1 + (size_t)S_TOK * NE * CAP;
        if (kA) {
            size_t idx = (size_t)t * NE * CAP + (size_t)ws->e1a[t] * CAP + loc;
            cw[idx] = g1 / d; dm[idx] = 1.f;
        }
        if (kB) {
            size_t idx = (size_t)t * NE * CAP + (size_t)ws->e2a[t] * CAP + loc;
            cw[idx] = g2 / d; dm[idx] = 1.f;
        }
    } else {
        int tid = threadIdx.x;
        if (tid >= 64) return;
        double part = 0.0;
        if (tid < NE) {
            int c = ws->counts[tid];
            out[1 + 2 * (size_t)S_TOK * NE * CAP + tid] = (float)c;
            double me = ws->gate_sum[tid] / (double)S_TOK;
            double ce = (double)c / (double)S_TOK;
            part = me * ce;
        }
        #pragma unroll
        for (int m = 16; m >= 1; m >>= 1) part += __shfl_xor(part, m);
        if (tid == 0) out[0] = (float)(part * 16.0);   // mean*E*E/K = sum*16
    }
}

extern "C" void kernel_launch(void* const* d_in, const int* in_sizes, int n_in,
                              void* d_out, int out_size, void* d_ws, size_t ws_size,
                              hipStream_t stream) {
    const float* x  = (const float*)d_in[0];
    const float* wg = (const float*)d_in[1];
    float* out = (float*)d_out;
    Ws* ws = (Ws*)d_ws;

    // zero-fill the entire output (combine + dispatch are >99.9% zeros);
    // scatter kernel then overwrites the <=2 nonzero slots per token.
    hipMemsetAsync(d_out, 0, (size_t)out_size * sizeof(float), stream);

    k_gate<<<S_TOK / TOKB, TPB, 0, stream>>>(x, wg, ws);
    k_capacity<<<NE, 256, 0, stream>>>(ws);
    k_scatter_final<<<17, 256, 0, stream>>>(ws, out);
}